// Round 11
// baseline (565.882 us; speedup 1.0000x reference)
//
#include <hip/hip_runtime.h>
#include <hip/hip_fp16.h>

// GCN critic: 4 layers (128->16->16->16->1), symmetric gcn_norm with self-loops,
// global mean pool. N=100000 nodes, E=6400000 edges.
// R18: k_aggd = wave-per-node agg with 16B-per-lane zs gathers (32 recs per
// gather instruction, 4x fewer gather insts) + fused next-layer dense epilogue
// (kills dense16 x2, dense1, and the acc round-trip; 11 -> 8 dispatches).
// sortB reverted to R16 8B-staging (82.7 us measured; R17 compress regressed).
// R15/16: block-contiguous fill + batched gather transpose. R14: wave scans.

#define BSHIFT 7
#define BSIZE 128            // nodes per dst bucket
#define NB_AL 784            // >= nblk=782, >= nbuck+1=783
#define CAPL 8960            // recs per bucket cap (mean 8184 + 8.6 sigma)
#define MSTRIDE 784          // meta ints per fill-block row (>= nbuck+1)
#define NSRC_MASK 131071     // 17-bit src
#define FBLK 512
#define FCHUNK 8192          // edges per fill block
#define FRPT (FCHUNK / FBLK) // 16
#define SBLK 512
#define RPT 18               // ceil(CAPL / SBLK)
#define LPB 13               // 13*64 = 832 >= 784 scan width

static __device__ __forceinline__ float relu_(float v) { return v > 0.f ? v : 0.f; }

static __device__ __forceinline__ float h2f_bits(unsigned short b) {
    __half_raw hr; hr.x = b;
    return __half2float(__half(hr));
}
static __device__ __forceinline__ unsigned short f2h_bits(float f) {
    __half h = __float2half(f);
    __half_raw hr = *(__half_raw*)&h;
    return hr.x;
}

// ---- fill: pass1 hist (atomicAdd return = in-(block,bucket) rank) ->
// wave0 shfl-scan -> rank-addressed LDS bucket-sorted staging ->
// LINEAR flush to block's own chunk + meta row. rec64 = w16<<32|dl<<17|src ----
__global__ __launch_bounds__(FBLK) void k_fill(const int* __restrict__ src, const int* __restrict__ dst,
                                               const float* __restrict__ w,
                                               unsigned long long* __restrict__ ep,
                                               int* __restrict__ scm, int E, int nbuck) {
    __shared__ unsigned long long stg[FCHUNK];   // 64 KB
    __shared__ int sc[NB_AL];
    __shared__ int hist[NB_AL];
    const int t = threadIdx.x;
    for (int i = t; i < nbuck; i += FBLK) hist[i] = 0;
    __syncthreads();
    const int c0 = blockIdx.x * FCHUNK;
    const int c1 = min(c0 + FCHUNK, E);
    unsigned pk[FRPT];
#pragma unroll
    for (int k = 0; k < FRPT; ++k) {
        int e = c0 + t + k * FBLK;
        if (e < c1) {
            int d_ = dst[e];
            int b = d_ >> BSHIFT;
            int rank = atomicAdd(&hist[b], 1);
            pk[k] = ((unsigned)b << 20) | ((unsigned)(d_ & (BSIZE - 1)) << 13) | (unsigned)rank;
        }
    }
    __syncthreads();
    if (t < 64) {
        const int i0 = t * LPB;
        int v[LPB];
        int tot = 0;
#pragma unroll
        for (int k = 0; k < LPB; ++k) {
            int i = i0 + k;
            v[k] = (i < nbuck) ? hist[i] : 0;
        }
#pragma unroll
        for (int k = 0; k < LPB; ++k) { int x = v[k]; v[k] = tot; tot += x; }
        int inc = tot;
#pragma unroll
        for (int d = 1; d < 64; d <<= 1) {
            int y = __shfl_up(inc, d, 64);
            if (t >= d) inc += y;
        }
        const int ex = inc - tot;
#pragma unroll
        for (int k = 0; k < LPB; ++k) {
            int i = i0 + k;
            if (i <= nbuck) sc[i] = ex + v[k];
        }
    }
    __syncthreads();
#pragma unroll
    for (int k = 0; k < FRPT; ++k) {
        int e = c0 + t + k * FBLK;
        if (e < c1) {
            unsigned p = pk[k];
            int b = p >> 20;
            unsigned dl = (p >> 13) & (BSIZE - 1);
            int rank = (int)(p & 8191u);
            stg[sc[b] + rank] = ((unsigned long long)f2h_bits(w[e]) << 32)
                              | (dl << 17) | (unsigned)src[e];
        }
    }
    __syncthreads();
    const int m = c1 - c0;
    for (int i = t; i < m; i += FBLK) ep[c0 + i] = stg[i];
    int* row = scm + (size_t)blockIdx.x * MSTRIDE;
    for (int i = t; i <= nbuck; i += FBLK) row[i] = sc[i];
}

// ---- stage B (R16 version): gather bucket b's runs (4 runs/group-iter, 4x
// outstanding loads) into 8B LDS, register-stage, hist+deg, shfl scan, scatter
// compressed 4B recs (src<<15|w15), coalesced writeback to epc (base=b*CAPL). ----
__global__ __launch_bounds__(SBLK) void k_sortB(const unsigned long long* __restrict__ ep,
                                                const int* __restrict__ scm,
                                                unsigned* __restrict__ epc, float* __restrict__ dis,
                                                int* __restrict__ rs, int* __restrict__ re,
                                                int n, int nbuck, int nblk) {
    __shared__ unsigned long long stg[CAPL];     // 70 KB (aliased as 4B after reg load)
    __shared__ int s_start[NB_AL];
    __shared__ unsigned short s_len[NB_AL];
    __shared__ unsigned short s_gex[NB_AL];
    __shared__ int hist[BSIZE];
    __shared__ int excl[BSIZE + 1];
    __shared__ int cur[BSIZE];
    __shared__ float degl[BSIZE];
    __shared__ int s_m;
    const int b = blockIdx.x, t = threadIdx.x;
    for (int j = t; j < nblk; j += SBLK) {
        const int* row = scm + (size_t)j * MSTRIDE;
        int s0 = row[b], s1 = row[b + 1];
        s_start[j] = j * FCHUNK + s0;
        s_len[j] = (unsigned short)(s1 - s0);
    }
    if (t < BSIZE) { hist[t] = 0; degl[t] = 0.f; }
    __syncthreads();
    if (t < 64) {
        const int i0 = t * LPB;
        int v[LPB];
        int tot = 0;
#pragma unroll
        for (int k = 0; k < LPB; ++k) {
            int i = i0 + k;
            v[k] = (i < nblk) ? (int)s_len[i] : 0;
        }
#pragma unroll
        for (int k = 0; k < LPB; ++k) { int x = v[k]; v[k] = tot; tot += x; }
        int inc = tot;
#pragma unroll
        for (int d = 1; d < 64; d <<= 1) {
            int y = __shfl_up(inc, d, 64);
            if (t >= d) inc += y;
        }
        const int ex = inc - tot;
#pragma unroll
        for (int k = 0; k < LPB; ++k) {
            int i = i0 + k;
            if (i < nblk) s_gex[i] = (unsigned short)min(ex + v[k], CAPL);
        }
        if (t == 63) s_m = min(inc, CAPL);
    }
    __syncthreads();
    const int cnt = s_m;
    // gather runs into LDS: 16-lane groups, 4 runs per iteration (4 MLW)
    const int grp = t >> 4, lgl = t & 15;        // 32 groups of 16 lanes
    for (int j0 = grp * 4; j0 < nblk; j0 += 128) {
        int a0 = 0, a1 = 0, a2 = 0, a3 = 0;
        int l0 = 0, l1 = 0, l2 = 0, l3 = 0;
        int g0 = 0, g1 = 0, g2 = 0, g3 = 0;
        a0 = s_start[j0]; l0 = s_len[j0]; g0 = s_gex[j0];
        if (j0 + 1 < nblk) { a1 = s_start[j0 + 1]; l1 = s_len[j0 + 1]; g1 = s_gex[j0 + 1]; }
        if (j0 + 2 < nblk) { a2 = s_start[j0 + 2]; l2 = s_len[j0 + 2]; g2 = s_gex[j0 + 2]; }
        if (j0 + 3 < nblk) { a3 = s_start[j0 + 3]; l3 = s_len[j0 + 3]; g3 = s_gex[j0 + 3]; }
        unsigned long long v0 = 0, v1 = 0, v2 = 0, v3 = 0;
        if (lgl < l0) v0 = ep[a0 + lgl];
        if (lgl < l1) v1 = ep[a1 + lgl];
        if (lgl < l2) v2 = ep[a2 + lgl];
        if (lgl < l3) v3 = ep[a3 + lgl];
        if (lgl < l0) { int p = g0 + lgl; if (p < CAPL) stg[p] = v0; }
        if (lgl < l1) { int p = g1 + lgl; if (p < CAPL) stg[p] = v1; }
        if (lgl < l2) { int p = g2 + lgl; if (p < CAPL) stg[p] = v2; }
        if (lgl < l3) { int p = g3 + lgl; if (p < CAPL) stg[p] = v3; }
        for (int l = 16 + lgl; l < l0; l += 16) { int p = g0 + l; if (p < CAPL) stg[p] = ep[a0 + l]; }
        for (int l = 16 + lgl; l < l1; l += 16) { int p = g1 + l; if (p < CAPL) stg[p] = ep[a1 + l]; }
        for (int l = 16 + lgl; l < l2; l += 16) { int p = g2 + l; if (p < CAPL) stg[p] = ep[a2 + l]; }
        for (int l = 16 + lgl; l < l3; l += 16) { int p = g3 + l; if (p < CAPL) stg[p] = ep[a3 + l]; }
    }
    __syncthreads();
    unsigned long long r[RPT];
#pragma unroll
    for (int k = 0; k < RPT; ++k) {
        int e = t + k * SBLK;
        if (e < cnt) r[k] = stg[e];
    }
    __syncthreads();
#pragma unroll
    for (int k = 0; k < RPT; ++k) {
        int e = t + k * SBLK;
        if (e < cnt) {
            int dl = ((unsigned)r[k] >> 17) & (BSIZE - 1);
            atomicAdd(&hist[dl], 1);
            atomicAdd(&degl[dl], h2f_bits((unsigned short)(r[k] >> 32)));
        }
    }
    __syncthreads();
    if (t < 64) {
        int a = hist[2 * t], c = hist[2 * t + 1];
        int tot = a + c;
        int inc = tot;
#pragma unroll
        for (int d = 1; d < 64; d <<= 1) {
            int y = __shfl_up(inc, d, 64);
            if (t >= d) inc += y;
        }
        int ex = inc - tot;
        excl[2 * t] = ex;
        excl[2 * t + 1] = ex + a;
        if (t == 63) excl[BSIZE] = inc;
    }
    __syncthreads();
    const int base4 = b * CAPL;
    if (t < BSIZE) {
        cur[t] = excl[t];
        int node = (b << BSHIFT) + t;
        if (node < n) {
            dis[node] = (float)(1.0 / sqrt((double)(degl[t] + 1.0f)));   // +1 self-loop
            rs[node] = base4 + excl[t];
            re[node] = base4 + excl[t] + hist[t];
        }
    }
    __syncthreads();
    unsigned* stg32 = (unsigned*)stg;
#pragma unroll
    for (int k = 0; k < RPT; ++k) {
        int e = t + k * SBLK;
        if (e < cnt) {
            int dl = ((unsigned)r[k] >> 17) & (BSIZE - 1);
            int pos = atomicAdd(&cur[dl], 1);
            stg32[pos] = (((unsigned)r[k] & NSRC_MASK) << 15) | ((unsigned)(r[k] >> 32) & 0x7FFF);
        }
    }
    __syncthreads();
    unsigned* outp = epc + base4;
    const int mm = excl[BSIZE];
    for (int i = t; i < mm; i += SBLK) outp[i] = stg32[i];
}

// ---- dense: zs = fp16( dis * (xin @ W) ); float4 activation loads ----
template<int FI, int FO, bool RELU>
__global__ __launch_bounds__(256) void k_dense(const float* __restrict__ xin, const float* __restrict__ W,
                                               const float* __restrict__ bprev, const float* __restrict__ dis,
                                               __half* __restrict__ zs, int n) {
    constexpr int NPB = 256 / FO;
    constexpr int XP = FI + 4;
    constexpr int F4 = FI / 4;
    __shared__ float Wl[FI * FO];
    __shared__ float xs[NPB * XP];
    const int t = threadIdx.x;
    for (int i = t; i < FI * FO; i += 256) Wl[i] = W[i];
    const int node0 = blockIdx.x * NPB;
    const float4* __restrict__ x4 = (const float4*)xin;
    for (int i = t; i < NPB * F4; i += 256) {
        int r = i / F4, c4 = i - r * F4;
        int node = node0 + r;
        float4 v = make_float4(0.f, 0.f, 0.f, 0.f);
        if (node < n) {
            v = x4[node * F4 + c4];
            if constexpr (RELU) {
                float4 bv = ((const float4*)bprev)[c4];
                v.x = relu_(v.x + bv.x); v.y = relu_(v.y + bv.y);
                v.z = relu_(v.z + bv.z); v.w = relu_(v.w + bv.w);
            }
        }
        *(float4*)&xs[r * XP + c4 * 4] = v;
    }
    __syncthreads();
    const int r = t / FO, j = t - r * FO;
    const int node = node0 + r;
    if (node < n) {
        float s = 0.f;
#pragma unroll
        for (int k = 0; k < FI; ++k) s += xs[r * XP + k] * Wl[k * FO + j];
        zs[node * FO + j] = __float2half(s * dis[node]);
    }
}

// ---- fused agg + next dense (R18): wave per node. Lane (g=lane>>1, j2=lane&1)
// gathers 16B (8 features) of rec g's zs row -> 32 recs per gather instruction.
// Reduce over g via shfl_xor(2..32). Epilogue: x=relu(A+bl); z=dis*(x@Wn).
// FINAL: Wn is 16x1, writes one half per node. ----
template<bool FINAL>
__global__ __launch_bounds__(256) void k_aggd(const unsigned* __restrict__ epc, const int* __restrict__ rs,
                                              const int* __restrict__ re, const float* __restrict__ dis,
                                              const __half* __restrict__ zsIn, const float* __restrict__ bl,
                                              const float* __restrict__ Wn, __half* __restrict__ zsOut,
                                              int n) {
    __shared__ float Wl[256];
    __shared__ float blv[16];
    const int t = threadIdx.x;
    if (FINAL) { if (t < 16) Wl[t] = Wn[t]; }
    else       { if (t < 256) Wl[t] = Wn[t]; }
    if (t < 16) blv[t] = bl[t];
    __syncthreads();
    const int wv = (blockIdx.x * 256 + t) >> 6;   // node (wave-uniform)
    if (wv >= n) return;
    const int lane = t & 63;
    const int g = lane >> 1, j2 = lane & 1;
    const float4* __restrict__ zs4 = (const float4*)zsIn;   // 16B = half of a zs row
    const int base = rs[wv], endv = re[wv];
    float s[8] = {0.f, 0.f, 0.f, 0.f, 0.f, 0.f, 0.f, 0.f};
    int e = base;
    for (; e + 63 < endv; e += 64) {              // 64 recs per iteration, 2 chains
        unsigned ra = epc[e + g], rb = epc[e + 32 + g];
        float4 qa = zs4[(ra >> 15) * 2 + j2];
        float4 qb = zs4[(rb >> 15) * 2 + j2];
        float wa = h2f_bits((unsigned short)(ra & 0x7FFF));
        float wb = h2f_bits((unsigned short)(rb & 0x7FFF));
        float2 a0 = __half22float2(*(__half2*)&qa.x), a1 = __half22float2(*(__half2*)&qa.y);
        float2 a2 = __half22float2(*(__half2*)&qa.z), a3 = __half22float2(*(__half2*)&qa.w);
        float2 b0 = __half22float2(*(__half2*)&qb.x), b1 = __half22float2(*(__half2*)&qb.y);
        float2 b2 = __half22float2(*(__half2*)&qb.z), b3 = __half22float2(*(__half2*)&qb.w);
        s[0] += a0.x * wa + b0.x * wb;  s[1] += a0.y * wa + b0.y * wb;
        s[2] += a1.x * wa + b1.x * wb;  s[3] += a1.y * wa + b1.y * wb;
        s[4] += a2.x * wa + b2.x * wb;  s[5] += a2.y * wa + b2.y * wb;
        s[6] += a3.x * wa + b3.x * wb;  s[7] += a3.y * wa + b3.y * wb;
    }
    for (; e < endv; e += 32) {                   // tail: 32 recs, lane-guarded
        if (e + g < endv) {
            unsigned ra = epc[e + g];
            float4 qa = zs4[(ra >> 15) * 2 + j2];
            float wa = h2f_bits((unsigned short)(ra & 0x7FFF));
            float2 a0 = __half22float2(*(__half2*)&qa.x), a1 = __half22float2(*(__half2*)&qa.y);
            float2 a2 = __half22float2(*(__half2*)&qa.z), a3 = __half22float2(*(__half2*)&qa.w);
            s[0] += a0.x * wa; s[1] += a0.y * wa; s[2] += a1.x * wa; s[3] += a1.y * wa;
            s[4] += a2.x * wa; s[5] += a2.y * wa; s[6] += a3.x * wa; s[7] += a3.y * wa;
        }
    }
    // reduce over g (lane bits 1..5); bit0 (j2) preserved
#pragma unroll
    for (int off = 2; off <= 32; off <<= 1) {
#pragma unroll
        for (int q = 0; q < 8; ++q) s[q] += __shfl_xor(s[q], off, 64);
    }
    // A_k = dis*(zself_k + s_k) for this lane's j2-half (all lanes hold their half)
    const float d = dis[wv];
    {
        float4 qz = zs4[wv * 2 + j2];
        float2 z0 = __half22float2(*(__half2*)&qz.x), z1 = __half22float2(*(__half2*)&qz.y);
        float2 z2 = __half22float2(*(__half2*)&qz.z), z3 = __half22float2(*(__half2*)&qz.w);
        s[0] = d * (z0.x + s[0]); s[1] = d * (z0.y + s[1]);
        s[2] = d * (z1.x + s[2]); s[3] = d * (z1.y + s[3]);
        s[4] = d * (z2.x + s[4]); s[5] = d * (z2.y + s[5]);
        s[6] = d * (z3.x + s[6]); s[7] = d * (z3.y + s[7]);
    }
    // epilogue dense: x_k = relu(A_k + bl_k); z_j = d * sum_k x_k * Wn[k][j]
    const int j = lane & 15;
    float z = 0.f;
#pragma unroll
    for (int k = 0; k < 16; ++k) {
        float Ak = __shfl(s[k & 7], k >> 3, 64);  // lane0: k<8, lane1: k>=8
        float xk = relu_(Ak + blv[k]);
        if (FINAL) z += xk * Wl[k];
        else       z += xk * Wl[k * 16 + j];
    }
    if (FINAL) {
        if (lane == 0) zsOut[wv] = __float2half(z * d);
    } else {
        if (lane < 16) zsOut[wv * 16 + j] = __float2half(z * d);
    }
}

// ---- aggregation FO=1 + relu+bias, per-block partial sums ----
__global__ __launch_bounds__(256) void k_agg1(const unsigned* __restrict__ epc, const int* __restrict__ rs,
                                              const int* __restrict__ re, const float* __restrict__ dis,
                                              const __half* __restrict__ zs1, const float* __restrict__ b4,
                                              float* __restrict__ partial, int n) {
    const int t = threadIdx.x;
    const int wv = (blockIdx.x * 256 + t) >> 6;
    const int lane = t & 63;
    float v = 0.f;
    if (wv < n) {
        const int base = rs[wv], end = re[wv];
        float s = 0.f;
        for (int e = base + lane; e < end; e += 64) {
            unsigned r = epc[e];
            s += __half2float(zs1[r >> 15]) * h2f_bits((unsigned short)(r & 0x7FFF));
        }
#pragma unroll
        for (int o = 32; o > 0; o >>= 1) s += __shfl_xor(s, o, 64);
        if (lane == 0) v = relu_(dis[wv] * (__half2float(zs1[wv]) + s) + b4[0]);
    }
    __shared__ float wsum[4];
    if (lane == 0) wsum[t >> 6] = v;
    __syncthreads();
    if (t == 0) partial[blockIdx.x] = wsum[0] + wsum[1] + wsum[2] + wsum[3];
}

// ---- final: out[0] = sum(partial) / n ; one block ----
__global__ __launch_bounds__(1024) void k_final(const float* __restrict__ partial, float* __restrict__ out,
                                                int nb, int n) {
    const int t = threadIdx.x;
    float s = 0.f;
    for (int i = t; i < nb; i += 1024) s += partial[i];
#pragma unroll
    for (int o = 32; o > 0; o >>= 1) s += __shfl_xor(s, o, 64);
    __shared__ float wsum[16];
    if ((t & 63) == 0) wsum[t >> 6] = s;
    __syncthreads();
    if (t == 0) {
        float tot = 0.f;
#pragma unroll
        for (int k = 0; k < 16; ++k) tot += wsum[k];
        out[0] = tot / (float)n;
    }
}

static inline size_t align_up(size_t x) { return (x + 255) & ~(size_t)255; }

extern "C" void kernel_launch(void* const* d_in, const int* in_sizes, int n_in,
                              void* d_out, int out_size, void* d_ws, size_t ws_size,
                              hipStream_t stream) {
    const float* vf  = (const float*)d_in[0];   // [N,128]
    const int*   edg = (const int*)d_in[1];     // [2,E] int32
    const float* w   = (const float*)d_in[2];   // [E]
    const float* W1  = (const float*)d_in[3];
    const float* b1  = (const float*)d_in[4];
    const float* W2  = (const float*)d_in[5];
    const float* b2  = (const float*)d_in[6];
    const float* W3  = (const float*)d_in[7];
    const float* b3  = (const float*)d_in[8];
    const float* W4  = (const float*)d_in[9];
    const float* b4  = (const float*)d_in[10];
    float* out = (float*)d_out;

    const int n = in_sizes[0] / 128;   // 100000
    const int E = in_sizes[2];         // 6400000
    const int* src = edg;
    const int* dst = edg + E;
    const int nbuck = (n + BSIZE - 1) >> BSHIFT;   // 782
    const int gB = (E + FCHUNK - 1) / FCHUNK;      // 782 fill blocks

    char* ws = (char*)d_ws;
    size_t off = 0;
    int*                rs      = (int*)(ws + off);                off += align_up((size_t)n * 4);
    int*                re      = (int*)(ws + off);                off += align_up((size_t)n * 4);
    float*              dis     = (float*)(ws + off);              off += align_up((size_t)n * 4);
    float*              partial = (float*)(ws + off);              off += align_up((size_t)((n + 3) / 4 + 1) * 4);
    unsigned long long* ep      = (unsigned long long*)(ws + off); off += align_up((size_t)E * 8);
    int*                scm     = (int*)(ws + off);                off += align_up((size_t)gB * MSTRIDE * 4);
    unsigned*           epc     = (unsigned*)(ws + off);           off += align_up((size_t)nbuck * CAPL * 4);
    __half*             zsA     = (__half*)(ws + off);             off += align_up((size_t)n * 16 * 2);
    __half*             zsB     = (__half*)(ws + off);             off += align_up((size_t)n * 16 * 2);
    __half*             zs1     = (__half*)(ws + off);             off += align_up((size_t)n * 2);
    (void)ws_size;

    const int gD16 = (n + 15) / 16;                      // dense FO=16: 16 nodes/block
    const int gW = (n + 3) / 4;                          // wave-per-node kernels

    k_fill<<<gB, FBLK, 0, stream>>>(src, dst, w, ep, scm, E, nbuck);
    k_sortB<<<nbuck, SBLK, 0, stream>>>(ep, scm, epc, dis, rs, re, n, nbuck, gB);

    // layer 1 dense: 128 -> 16
    k_dense<128, 16, false><<<gD16, 256, 0, stream>>>(vf, W1, nullptr, dis, zsA, n);
    // fused agg(L1)+dense(L2), agg(L2)+dense(L3), agg(L3)+dense(L4: 16->1)
    k_aggd<false><<<gW, 256, 0, stream>>>(epc, rs, re, dis, zsA, b1, W2, zsB, n);
    k_aggd<false><<<gW, 256, 0, stream>>>(epc, rs, re, dis, zsB, b2, W3, zsA, n);
    k_aggd<true ><<<gW, 256, 0, stream>>>(epc, rs, re, dis, zsA, b3, W4, zs1, n);
    // layer 4 aggregation + relu+bias into per-block partials, then mean
    k_agg1<<<gW, 256, 0, stream>>>(epc, rs, re, dis, zs1, b4, partial, n);
    k_final<<<1, 1024, 0, stream>>>(partial, out, gW, n);
}

// Round 12
// 454.104 us; speedup vs baseline: 1.2462x; 1.2462x over previous
//
#include <hip/hip_runtime.h>
#include <hip/hip_fp16.h>

// GCN critic: 4 layers (128->16->16->16->1), symmetric gcn_norm with self-loops,
// global mean pool. N=100000 nodes, E=6400000 edges.
// R19: back to R17's measured-best structure (469us). k_aggdB = R17 agg16B +
// BLOCK-LEVEL fused dense epilogue (LDS xloc, one barrier, amortized 16x16
// matmul) -- not R18's wave-level shfl fusion (90us, VALU-bound regression).
// sortB = R16 8B-staging (82.7us measured; R17 compress was 90.5).
// R15/16: block-contiguous fill + batched gather transpose. R14: wave scans.

#define BSHIFT 7
#define BSIZE 128            // nodes per dst bucket
#define NB_AL 784            // >= nblk=782, >= nbuck+1=783
#define CAPL 8960            // recs per bucket cap (mean 8184 + 8.6 sigma)
#define MSTRIDE 784          // meta ints per fill-block row (>= nbuck+1)
#define NSRC_MASK 131071     // 17-bit src
#define FBLK 512
#define FCHUNK 8192          // edges per fill block
#define FRPT (FCHUNK / FBLK) // 16
#define SBLK 512
#define RPT 18               // ceil(CAPL / SBLK)
#define LPB 13               // 13*64 = 832 >= 784 scan width
#define ANODES 16            // nodes per agg block
#define ACAP 3072            // staged recs cap (mean ~1024)

static __device__ __forceinline__ float relu_(float v) { return v > 0.f ? v : 0.f; }

static __device__ __forceinline__ float h2f_bits(unsigned short b) {
    __half_raw hr; hr.x = b;
    return __half2float(__half(hr));
}
static __device__ __forceinline__ unsigned short f2h_bits(float f) {
    __half h = __float2half(f);
    __half_raw hr = *(__half_raw*)&h;
    return hr.x;
}

// ---- fill: pass1 hist (atomicAdd return = in-(block,bucket) rank) ->
// wave0 shfl-scan -> rank-addressed LDS bucket-sorted staging ->
// LINEAR flush to block's own chunk + meta row. rec64 = w16<<32|dl<<17|src ----
__global__ __launch_bounds__(FBLK) void k_fill(const int* __restrict__ src, const int* __restrict__ dst,
                                               const float* __restrict__ w,
                                               unsigned long long* __restrict__ ep,
                                               int* __restrict__ scm, int E, int nbuck) {
    __shared__ unsigned long long stg[FCHUNK];   // 64 KB
    __shared__ int sc[NB_AL];
    __shared__ int hist[NB_AL];
    const int t = threadIdx.x;
    for (int i = t; i < nbuck; i += FBLK) hist[i] = 0;
    __syncthreads();
    const int c0 = blockIdx.x * FCHUNK;
    const int c1 = min(c0 + FCHUNK, E);
    unsigned pk[FRPT];
#pragma unroll
    for (int k = 0; k < FRPT; ++k) {
        int e = c0 + t + k * FBLK;
        if (e < c1) {
            int d_ = dst[e];
            int b = d_ >> BSHIFT;
            int rank = atomicAdd(&hist[b], 1);
            pk[k] = ((unsigned)b << 20) | ((unsigned)(d_ & (BSIZE - 1)) << 13) | (unsigned)rank;
        }
    }
    __syncthreads();
    if (t < 64) {
        const int i0 = t * LPB;
        int v[LPB];
        int tot = 0;
#pragma unroll
        for (int k = 0; k < LPB; ++k) {
            int i = i0 + k;
            v[k] = (i < nbuck) ? hist[i] : 0;
        }
#pragma unroll
        for (int k = 0; k < LPB; ++k) { int x = v[k]; v[k] = tot; tot += x; }
        int inc = tot;
#pragma unroll
        for (int d = 1; d < 64; d <<= 1) {
            int y = __shfl_up(inc, d, 64);
            if (t >= d) inc += y;
        }
        const int ex = inc - tot;
#pragma unroll
        for (int k = 0; k < LPB; ++k) {
            int i = i0 + k;
            if (i <= nbuck) sc[i] = ex + v[k];
        }
    }
    __syncthreads();
#pragma unroll
    for (int k = 0; k < FRPT; ++k) {
        int e = c0 + t + k * FBLK;
        if (e < c1) {
            unsigned p = pk[k];
            int b = p >> 20;
            unsigned dl = (p >> 13) & (BSIZE - 1);
            int rank = (int)(p & 8191u);
            stg[sc[b] + rank] = ((unsigned long long)f2h_bits(w[e]) << 32)
                              | (dl << 17) | (unsigned)src[e];
        }
    }
    __syncthreads();
    const int m = c1 - c0;
    for (int i = t; i < m; i += FBLK) ep[c0 + i] = stg[i];
    int* row = scm + (size_t)blockIdx.x * MSTRIDE;
    for (int i = t; i <= nbuck; i += FBLK) row[i] = sc[i];
}

// ---- stage B (R16 version): gather bucket b's runs (4 runs/group-iter, 4x
// outstanding loads) into 8B LDS, register-stage, hist+deg, shfl scan, scatter
// compressed 4B recs (src<<15|w15), coalesced writeback to epc (base=b*CAPL). ----
__global__ __launch_bounds__(SBLK) void k_sortB(const unsigned long long* __restrict__ ep,
                                                const int* __restrict__ scm,
                                                unsigned* __restrict__ epc, float* __restrict__ dis,
                                                int* __restrict__ rs, int* __restrict__ re,
                                                int n, int nbuck, int nblk) {
    __shared__ unsigned long long stg[CAPL];     // 70 KB (aliased as 4B after reg load)
    __shared__ int s_start[NB_AL];
    __shared__ unsigned short s_len[NB_AL];
    __shared__ unsigned short s_gex[NB_AL];
    __shared__ int hist[BSIZE];
    __shared__ int excl[BSIZE + 1];
    __shared__ int cur[BSIZE];
    __shared__ float degl[BSIZE];
    __shared__ int s_m;
    const int b = blockIdx.x, t = threadIdx.x;
    for (int j = t; j < nblk; j += SBLK) {
        const int* row = scm + (size_t)j * MSTRIDE;
        int s0 = row[b], s1 = row[b + 1];
        s_start[j] = j * FCHUNK + s0;
        s_len[j] = (unsigned short)(s1 - s0);
    }
    if (t < BSIZE) { hist[t] = 0; degl[t] = 0.f; }
    __syncthreads();
    if (t < 64) {
        const int i0 = t * LPB;
        int v[LPB];
        int tot = 0;
#pragma unroll
        for (int k = 0; k < LPB; ++k) {
            int i = i0 + k;
            v[k] = (i < nblk) ? (int)s_len[i] : 0;
        }
#pragma unroll
        for (int k = 0; k < LPB; ++k) { int x = v[k]; v[k] = tot; tot += x; }
        int inc = tot;
#pragma unroll
        for (int d = 1; d < 64; d <<= 1) {
            int y = __shfl_up(inc, d, 64);
            if (t >= d) inc += y;
        }
        const int ex = inc - tot;
#pragma unroll
        for (int k = 0; k < LPB; ++k) {
            int i = i0 + k;
            if (i < nblk) s_gex[i] = (unsigned short)min(ex + v[k], CAPL);
        }
        if (t == 63) s_m = min(inc, CAPL);
    }
    __syncthreads();
    const int cnt = s_m;
    // gather runs into LDS: 16-lane groups, 4 runs per iteration (4 MLW)
    const int grp = t >> 4, lgl = t & 15;        // 32 groups of 16 lanes
    for (int j0 = grp * 4; j0 < nblk; j0 += 128) {
        int a0 = 0, a1 = 0, a2 = 0, a3 = 0;
        int l0 = 0, l1 = 0, l2 = 0, l3 = 0;
        int g0 = 0, g1 = 0, g2 = 0, g3 = 0;
        a0 = s_start[j0]; l0 = s_len[j0]; g0 = s_gex[j0];
        if (j0 + 1 < nblk) { a1 = s_start[j0 + 1]; l1 = s_len[j0 + 1]; g1 = s_gex[j0 + 1]; }
        if (j0 + 2 < nblk) { a2 = s_start[j0 + 2]; l2 = s_len[j0 + 2]; g2 = s_gex[j0 + 2]; }
        if (j0 + 3 < nblk) { a3 = s_start[j0 + 3]; l3 = s_len[j0 + 3]; g3 = s_gex[j0 + 3]; }
        unsigned long long v0 = 0, v1 = 0, v2 = 0, v3 = 0;
        if (lgl < l0) v0 = ep[a0 + lgl];
        if (lgl < l1) v1 = ep[a1 + lgl];
        if (lgl < l2) v2 = ep[a2 + lgl];
        if (lgl < l3) v3 = ep[a3 + lgl];
        if (lgl < l0) { int p = g0 + lgl; if (p < CAPL) stg[p] = v0; }
        if (lgl < l1) { int p = g1 + lgl; if (p < CAPL) stg[p] = v1; }
        if (lgl < l2) { int p = g2 + lgl; if (p < CAPL) stg[p] = v2; }
        if (lgl < l3) { int p = g3 + lgl; if (p < CAPL) stg[p] = v3; }
        for (int l = 16 + lgl; l < l0; l += 16) { int p = g0 + l; if (p < CAPL) stg[p] = ep[a0 + l]; }
        for (int l = 16 + lgl; l < l1; l += 16) { int p = g1 + l; if (p < CAPL) stg[p] = ep[a1 + l]; }
        for (int l = 16 + lgl; l < l2; l += 16) { int p = g2 + l; if (p < CAPL) stg[p] = ep[a2 + l]; }
        for (int l = 16 + lgl; l < l3; l += 16) { int p = g3 + l; if (p < CAPL) stg[p] = ep[a3 + l]; }
    }
    __syncthreads();
    unsigned long long r[RPT];
#pragma unroll
    for (int k = 0; k < RPT; ++k) {
        int e = t + k * SBLK;
        if (e < cnt) r[k] = stg[e];
    }
    __syncthreads();
#pragma unroll
    for (int k = 0; k < RPT; ++k) {
        int e = t + k * SBLK;
        if (e < cnt) {
            int dl = ((unsigned)r[k] >> 17) & (BSIZE - 1);
            atomicAdd(&hist[dl], 1);
            atomicAdd(&degl[dl], h2f_bits((unsigned short)(r[k] >> 32)));
        }
    }
    __syncthreads();
    if (t < 64) {
        int a = hist[2 * t], c = hist[2 * t + 1];
        int tot = a + c;
        int inc = tot;
#pragma unroll
        for (int d = 1; d < 64; d <<= 1) {
            int y = __shfl_up(inc, d, 64);
            if (t >= d) inc += y;
        }
        int ex = inc - tot;
        excl[2 * t] = ex;
        excl[2 * t + 1] = ex + a;
        if (t == 63) excl[BSIZE] = inc;
    }
    __syncthreads();
    const int base4 = b * CAPL;
    if (t < BSIZE) {
        cur[t] = excl[t];
        int node = (b << BSHIFT) + t;
        if (node < n) {
            dis[node] = (float)(1.0 / sqrt((double)(degl[t] + 1.0f)));   // +1 self-loop
            rs[node] = base4 + excl[t];
            re[node] = base4 + excl[t] + hist[t];
        }
    }
    __syncthreads();
    unsigned* stg32 = (unsigned*)stg;
#pragma unroll
    for (int k = 0; k < RPT; ++k) {
        int e = t + k * SBLK;
        if (e < cnt) {
            int dl = ((unsigned)r[k] >> 17) & (BSIZE - 1);
            int pos = atomicAdd(&cur[dl], 1);
            stg32[pos] = (((unsigned)r[k] & NSRC_MASK) << 15) | ((unsigned)(r[k] >> 32) & 0x7FFF);
        }
    }
    __syncthreads();
    unsigned* outp = epc + base4;
    const int mm = excl[BSIZE];
    for (int i = t; i < mm; i += SBLK) outp[i] = stg32[i];
}

// ---- dense: zs = fp16( dis * (xin @ W) ); float4 activation loads ----
template<int FI, int FO, bool RELU>
__global__ __launch_bounds__(256) void k_dense(const float* __restrict__ xin, const float* __restrict__ W,
                                               const float* __restrict__ bprev, const float* __restrict__ dis,
                                               __half* __restrict__ zs, int n) {
    constexpr int NPB = 256 / FO;
    constexpr int XP = FI + 4;
    constexpr int F4 = FI / 4;
    __shared__ float Wl[FI * FO];
    __shared__ float xs[NPB * XP];
    const int t = threadIdx.x;
    for (int i = t; i < FI * FO; i += 256) Wl[i] = W[i];
    const int node0 = blockIdx.x * NPB;
    const float4* __restrict__ x4 = (const float4*)xin;
    for (int i = t; i < NPB * F4; i += 256) {
        int r = i / F4, c4 = i - r * F4;
        int node = node0 + r;
        float4 v = make_float4(0.f, 0.f, 0.f, 0.f);
        if (node < n) {
            v = x4[node * F4 + c4];
            if constexpr (RELU) {
                float4 bv = ((const float4*)bprev)[c4];
                v.x = relu_(v.x + bv.x); v.y = relu_(v.y + bv.y);
                v.z = relu_(v.z + bv.z); v.w = relu_(v.w + bv.w);
            }
        }
        *(float4*)&xs[r * XP + c4 * 4] = v;
    }
    __syncthreads();
    const int r = t / FO, j = t - r * FO;
    const int node = node0 + r;
    if (node < n) {
        float s = 0.f;
#pragma unroll
        for (int k = 0; k < FI; ++k) s += xs[r * XP + k] * Wl[k * FO + j];
        zs[node * FO + j] = __float2half(s * dis[node]);
    }
}

// ---- fused agg + next dense (R19): R17's block-per-16-nodes agg (LDS rec
// staging, 8 feature-lanes x 8 edge-groups) + BLOCK-LEVEL dense epilogue:
// waves write x=relu(A+bl) into LDS xloc, one barrier, 256 threads compute
// the 16x16 (or 16x1) matmul amortized. Kills dense16 x2 / dense1 / acc. ----
template<bool FINAL>
__global__ __launch_bounds__(256) void k_aggdB(const unsigned* __restrict__ epc, const int* __restrict__ rs,
                                               const int* __restrict__ re, const float* __restrict__ dis,
                                               const __half* __restrict__ zsIn, const float* __restrict__ bl,
                                               const float* __restrict__ Wn, __half* __restrict__ zsOut,
                                               int n) {
    __shared__ unsigned stg[ACAP];               // 12 KB
    __shared__ float Wl[256];
    __shared__ float blv[16];
    __shared__ float xloc[ANODES][16];
    __shared__ float dloc[ANODES];
    const int bid = blockIdx.x;
    const int bucket = bid >> 3;
    const int node0 = (bucket << BSHIFT) + ((bid & 7) << 4);
    if (node0 >= n) return;
    const int t = threadIdx.x;
    if (FINAL) { if (t < 16) Wl[t] = Wn[t]; }
    else       { if (t < 256) Wl[t] = Wn[t]; }
    if (t >= 256 - 16) blv[t - (256 - 16)] = bl[t - (256 - 16)];
    const int last = min(node0 + ANODES - 1, n - 1);
    const int s0 = rs[node0];
    const int s1 = re[last];
    const int len = s1 - s0;
    const bool useLds = (len <= ACAP);
    if (useLds) {
        for (int i = t; i < len; i += 256) stg[i] = epc[s0 + i];
    }
    __syncthreads();
    const int wave = t >> 6, lane = t & 63;
    const int j2 = lane & 7, g = lane >> 3;
    const __half2* __restrict__ zs2 = (const __half2*)zsIn;
#pragma unroll
    for (int k = 0; k < 4; ++k) {
        const int node = node0 + (wave << 2) + k;
        if (node >= n) break;
        const int base = rs[node] - s0, endn = re[node] - s0;
        float sx = 0.f, sy = 0.f;
        int e = base + g;
        if (useLds) {
            for (; e + 24 < endn; e += 32) {
                unsigned r0 = stg[e], r1 = stg[e + 8], r2 = stg[e + 16], r3 = stg[e + 24];
                __half2 z0 = zs2[(r0 >> 15) * 8 + j2];
                __half2 z1 = zs2[(r1 >> 15) * 8 + j2];
                __half2 z2 = zs2[(r2 >> 15) * 8 + j2];
                __half2 z3 = zs2[(r3 >> 15) * 8 + j2];
                float w0 = h2f_bits((unsigned short)(r0 & 0x7FFF));
                float w1 = h2f_bits((unsigned short)(r1 & 0x7FFF));
                float w2 = h2f_bits((unsigned short)(r2 & 0x7FFF));
                float w3 = h2f_bits((unsigned short)(r3 & 0x7FFF));
                float2 f0 = __half22float2(z0), f1 = __half22float2(z1);
                float2 f2 = __half22float2(z2), f3 = __half22float2(z3);
                sx += f0.x * w0 + f1.x * w1 + f2.x * w2 + f3.x * w3;
                sy += f0.y * w0 + f1.y * w1 + f2.y * w2 + f3.y * w3;
            }
            for (; e < endn; e += 8) {
                unsigned r0 = stg[e];
                float w0 = h2f_bits((unsigned short)(r0 & 0x7FFF));
                float2 f0 = __half22float2(zs2[(r0 >> 15) * 8 + j2]);
                sx += f0.x * w0;
                sy += f0.y * w0;
            }
        } else {
            for (; e + 24 < endn; e += 32) {
                unsigned r0 = epc[s0 + e], r1 = epc[s0 + e + 8], r2 = epc[s0 + e + 16], r3 = epc[s0 + e + 24];
                __half2 z0 = zs2[(r0 >> 15) * 8 + j2];
                __half2 z1 = zs2[(r1 >> 15) * 8 + j2];
                __half2 z2 = zs2[(r2 >> 15) * 8 + j2];
                __half2 z3 = zs2[(r3 >> 15) * 8 + j2];
                float w0 = h2f_bits((unsigned short)(r0 & 0x7FFF));
                float w1 = h2f_bits((unsigned short)(r1 & 0x7FFF));
                float w2 = h2f_bits((unsigned short)(r2 & 0x7FFF));
                float w3 = h2f_bits((unsigned short)(r3 & 0x7FFF));
                float2 f0 = __half22float2(z0), f1 = __half22float2(z1);
                float2 f2 = __half22float2(z2), f3 = __half22float2(z3);
                sx += f0.x * w0 + f1.x * w1 + f2.x * w2 + f3.x * w3;
                sy += f0.y * w0 + f1.y * w1 + f2.y * w2 + f3.y * w3;
            }
            for (; e < endn; e += 8) {
                unsigned r0 = epc[s0 + e];
                float w0 = h2f_bits((unsigned short)(r0 & 0x7FFF));
                float2 f0 = __half22float2(zs2[(r0 >> 15) * 8 + j2]);
                sx += f0.x * w0;
                sy += f0.y * w0;
            }
        }
        sx += __shfl_xor(sx, 8, 64);  sy += __shfl_xor(sy, 8, 64);
        sx += __shfl_xor(sx, 16, 64); sy += __shfl_xor(sy, 16, 64);
        sx += __shfl_xor(sx, 32, 64); sy += __shfl_xor(sy, 32, 64);
        if (g == 0) {
            float2 zself = __half22float2(zs2[node * 8 + j2]);
            float d = dis[node];
            const int nl = (wave << 2) + k;
            xloc[nl][2 * j2]     = relu_(d * (zself.x + sx) + blv[2 * j2]);
            xloc[nl][2 * j2 + 1] = relu_(d * (zself.y + sy) + blv[2 * j2 + 1]);
            if (j2 == 0) dloc[nl] = d;
        }
    }
    __syncthreads();
    // block-level dense epilogue (amortized)
    if (FINAL) {
        if (t < ANODES) {
            int node = node0 + t;
            if (node < n) {
                float z = 0.f;
#pragma unroll
                for (int k = 0; k < 16; ++k) z += xloc[t][k] * Wl[k];
                zsOut[node] = __float2half(z * dloc[t]);
            }
        }
    } else {
        const int nl = t >> 4, j = t & 15;
        int node = node0 + nl;
        if (node < n) {
            float z = 0.f;
#pragma unroll
            for (int k = 0; k < 16; ++k) z += xloc[nl][k] * Wl[k * 16 + j];
            zsOut[node * 16 + j] = __float2half(z * dloc[nl]);
        }
    }
}

// ---- aggregation FO=1 + relu+bias, per-block partial sums ----
__global__ __launch_bounds__(256) void k_agg1(const unsigned* __restrict__ epc, const int* __restrict__ rs,
                                              const int* __restrict__ re, const float* __restrict__ dis,
                                              const __half* __restrict__ zs1, const float* __restrict__ b4,
                                              float* __restrict__ partial, int n) {
    const int t = threadIdx.x;
    const int wv = (blockIdx.x * 256 + t) >> 6;
    const int lane = t & 63;
    float v = 0.f;
    if (wv < n) {
        const int base = rs[wv], end = re[wv];
        float s = 0.f;
        for (int e = base + lane; e < end; e += 64) {
            unsigned r = epc[e];
            s += __half2float(zs1[r >> 15]) * h2f_bits((unsigned short)(r & 0x7FFF));
        }
#pragma unroll
        for (int o = 32; o > 0; o >>= 1) s += __shfl_xor(s, o, 64);
        if (lane == 0) v = relu_(dis[wv] * (__half2float(zs1[wv]) + s) + b4[0]);
    }
    __shared__ float wsum[4];
    if (lane == 0) wsum[t >> 6] = v;
    __syncthreads();
    if (t == 0) partial[blockIdx.x] = wsum[0] + wsum[1] + wsum[2] + wsum[3];
}

// ---- final: out[0] = sum(partial) / n ; one block ----
__global__ __launch_bounds__(1024) void k_final(const float* __restrict__ partial, float* __restrict__ out,
                                                int nb, int n) {
    const int t = threadIdx.x;
    float s = 0.f;
    for (int i = t; i < nb; i += 1024) s += partial[i];
#pragma unroll
    for (int o = 32; o > 0; o >>= 1) s += __shfl_xor(s, o, 64);
    __shared__ float wsum[16];
    if ((t & 63) == 0) wsum[t >> 6] = s;
    __syncthreads();
    if (t == 0) {
        float tot = 0.f;
#pragma unroll
        for (int k = 0; k < 16; ++k) tot += wsum[k];
        out[0] = tot / (float)n;
    }
}

static inline size_t align_up(size_t x) { return (x + 255) & ~(size_t)255; }

extern "C" void kernel_launch(void* const* d_in, const int* in_sizes, int n_in,
                              void* d_out, int out_size, void* d_ws, size_t ws_size,
                              hipStream_t stream) {
    const float* vf  = (const float*)d_in[0];   // [N,128]
    const int*   edg = (const int*)d_in[1];     // [2,E] int32
    const float* w   = (const float*)d_in[2];   // [E]
    const float* W1  = (const float*)d_in[3];
    const float* b1  = (const float*)d_in[4];
    const float* W2  = (const float*)d_in[5];
    const float* b2  = (const float*)d_in[6];
    const float* W3  = (const float*)d_in[7];
    const float* b3  = (const float*)d_in[8];
    const float* W4  = (const float*)d_in[9];
    const float* b4  = (const float*)d_in[10];
    float* out = (float*)d_out;

    const int n = in_sizes[0] / 128;   // 100000
    const int E = in_sizes[2];         // 6400000
    const int* src = edg;
    const int* dst = edg + E;
    const int nbuck = (n + BSIZE - 1) >> BSHIFT;   // 782
    const int gB = (E + FCHUNK - 1) / FCHUNK;      // 782 fill blocks

    char* ws = (char*)d_ws;
    size_t off = 0;
    int*                rs      = (int*)(ws + off);                off += align_up((size_t)n * 4);
    int*                re      = (int*)(ws + off);                off += align_up((size_t)n * 4);
    float*              dis     = (float*)(ws + off);              off += align_up((size_t)n * 4);
    float*              partial = (float*)(ws + off);              off += align_up((size_t)((n + 3) / 4 + 1) * 4);
    unsigned long long* ep      = (unsigned long long*)(ws + off); off += align_up((size_t)E * 8);
    int*                scm     = (int*)(ws + off);                off += align_up((size_t)gB * MSTRIDE * 4);
    unsigned*           epc     = (unsigned*)(ws + off);           off += align_up((size_t)nbuck * CAPL * 4);
    __half*             zsA     = (__half*)(ws + off);             off += align_up((size_t)n * 16 * 2);
    __half*             zsB     = (__half*)(ws + off);             off += align_up((size_t)n * 16 * 2);
    __half*             zs1     = (__half*)(ws + off);             off += align_up((size_t)n * 2);
    (void)ws_size;

    const int gD16 = (n + 15) / 16;                      // dense FO=16: 16 nodes/block
    const int gW = (n + 3) / 4;                          // wave-per-node (agg1)
    const int gA = nbuck * 8;                            // aggdB: 16 nodes/block

    k_fill<<<gB, FBLK, 0, stream>>>(src, dst, w, ep, scm, E, nbuck);
    k_sortB<<<nbuck, SBLK, 0, stream>>>(ep, scm, epc, dis, rs, re, n, nbuck, gB);

    // layer 1 dense: 128 -> 16
    k_dense<128, 16, false><<<gD16, 256, 0, stream>>>(vf, W1, nullptr, dis, zsA, n);
    // fused agg(L1)+dense(L2), agg(L2)+dense(L3), agg(L3)+dense(L4: 16->1)
    k_aggdB<false><<<gA, 256, 0, stream>>>(epc, rs, re, dis, zsA, b1, W2, zsB, n);
    k_aggdB<false><<<gA, 256, 0, stream>>>(epc, rs, re, dis, zsB, b2, W3, zsA, n);
    k_aggdB<true ><<<gA, 256, 0, stream>>>(epc, rs, re, dis, zsA, b3, W4, zs1, n);
    // layer 4 aggregation + relu+bias into per-block partials, then mean
    k_agg1<<<gW, 256, 0, stream>>>(epc, rs, re, dis, zs1, b4, partial, n);
    k_final<<<1, 1024, 0, stream>>>(partial, out, gW, n);
}